// Round 3
// baseline (282.798 us; speedup 1.0000x reference)
//
#include <hip/hip_runtime.h>

// ---------------------------------------------------------------------------
// LeNet5-KAN on MI355X.  R3: weights via VMEM (vmcnt) instead of SMEM (lgkmcnt)
// with explicit 2-deep A/B prefetch rotation; conv1 re-tiled to 3-row bands.
// Spline: uniform knots => cardinal cubic B-spline closed form.
//   u = 2.5x + 5.5 ; cell i = floor(u), w = u - i
//   nonzero bases j=i-3..i: {(1-w)^3, 3w^3-6w^2+4, -3w^3+3w^2+3w+1, w^3}/6
// Feature row per element (12 floats, 9 used): f[0..7]=bases, f[8]=relu(x).
// ---------------------------------------------------------------------------

#define ONE_SIXTH 0.16666666666666666f

__device__ __forceinline__ void spline_feats(float v, float* __restrict__ f) {
    float u  = 2.5f * v + 5.5f;
    bool valid = (u >= 0.0f) && (u < 11.0f);
    float fi = floorf(u);
    int   i  = (int)fi;
    float w  = u - fi;
    float omw = 1.0f - w;
    float w2 = w * w, w3 = w2 * w;
    float c0 = omw * omw * omw * ONE_SIXTH;
    float c1 = (3.0f * w3 - 6.0f * w2 + 4.0f) * ONE_SIXTH;
    float c2 = (-3.0f * w3 + 3.0f * w2 + 3.0f * w + 1.0f) * ONE_SIXTH;
    float c3 = w3 * ONE_SIXTH;
    int j0 = i - 3;
#pragma unroll
    for (int j = 0; j < 8; ++j) {
        int d = j - j0;
        float val = (d == 0) ? c0 : (d == 1) ? c1 : (d == 2) ? c2 : (d == 3) ? c3 : 0.0f;
        f[j] = valid ? val : 0.0f;
    }
    f[8] = fmaxf(v, 0.0f);
    f[9] = 0.0f; f[10] = 0.0f; f[11] = 0.0f;
}

__device__ __forceinline__ void store_feat_row(float* __restrict__ dst,
                                               const float* __restrict__ f) {
    *(float4*)(dst)     = *(const float4*)(f);
    *(float4*)(dst + 4) = *(const float4*)(f + 4);
    *(float4*)(dst + 8) = *(const float4*)(f + 8);
}

// dot of feature row (s0,s1,rr) with 9 weights at w[off..off+8]
#define FMA9(acc, w, off)                                                     \
    acc += s0.x * (w)[(off) + 0] + s0.y * (w)[(off) + 1] +                    \
           s0.z * (w)[(off) + 2] + s0.w * (w)[(off) + 3] +                    \
           s1.x * (w)[(off) + 4] + s1.y * (w)[(off) + 5] +                    \
           s1.z * (w)[(off) + 6] + s1.w * (w)[(off) + 7] +                    \
           rr  * (w)[(off) + 8];

// ---------------------------------------------------------------------------
// K0: repack weights.
// W1c[tap][g][32] (g<2): slot oo*9+k, o=g*3+oo (o<6): k<8 spline*scaler, k==8 base.
// W2q[tap*4+g][40] (g<4): slot oo*9+k, o=g*4+oo (o<16), same scheme.
// zb[0] = 0 (runtime zero for the divergence trick).
// ---------------------------------------------------------------------------
__global__ __launch_bounds__(256) void k_prep(
    const float* __restrict__ c1_bw, const float* __restrict__ c1_sw,
    const float* __restrict__ c1_sc,
    const float* __restrict__ c2_bw, const float* __restrict__ c2_sw,
    const float* __restrict__ c2_sc,
    float* __restrict__ W1c, float* __restrict__ W2q, int* __restrict__ zb)
{
    int t = blockIdx.x * 256 + threadIdx.x;
    if (t == 0) zb[0] = 0;
    if (t < 1600) {                       // 25 taps * 2 g * 32
        int tap = t >> 6, s = t & 63;
        int g = s >> 5, s2 = s & 31;
        float v = 0.0f;
        if (s2 < 27) {
            int oo = s2 / 9, k = s2 - oo * 9;
            int o = g * 3 + oo;
            v = (k == 8) ? c1_bw[o * 25 + tap]
                         : c1_sw[(o * 25 + tap) * 8 + k] * c1_sc[o * 25 + tap];
        }
        W1c[t] = v;
    }
    if (t < 24000) {                      // 600 rows * 40
        int row = t / 40, s = t - row * 40;
        int tap = row >> 2, g = row & 3;
        float v = 0.0f;
        if (s < 36) {
            int oo = s / 9, k = s - oo * 9;
            int o = g * 4 + oo;
            v = (k == 8) ? c2_bw[o * 150 + tap]
                         : c2_sw[(o * 150 + tap) * 8 + k] * c2_sc[o * 150 + tap];
        }
        W2q[t] = v;
    }
}

// ---------------------------------------------------------------------------
// K1: conv1 + pool.  Block = (image, row-band of 8 conv rows). 384 threads =
// 2 out-groups (3 ch each, wave-uniform) x 192 px (8 rows x 24 cols).
// Weights per tap: 7 float4 via VMEM, A/B prefetch rotation.
// ---------------------------------------------------------------------------
__global__ __launch_bounds__(384) void k_conv1(
    const float* __restrict__ x, const float* __restrict__ W1c,
    const int* __restrict__ zp, float* __restrict__ h1)
{
    __shared__ float feat[336 * 12];     // 12 input rows x 28 cols
    __shared__ float cstage[6][200];
    const int blk = blockIdx.x;
    const int img = blk / 3, band = blk - img * 3;
    const int tid = threadIdx.x;
    const float* xb = x + img * 784 + band * 224;   // rows 8*band .. 8*band+11

    for (int e = tid; e < 336; e += 384) {
        float fr[12];
        spline_feats(xb[e], fr);
        store_feat_row(&feat[e * 12], fr);
    }
    __syncthreads();

    const int zf = (int)tid * zp[0];                 // runtime 0, divergent
    const int g   = tid / 192;                       // 0..1, wave-uniform
    const int px  = tid - g * 192;
    const int row = px / 24, col = px - row * 24;
    const int fbase = row * 28 + col;
    const float4* wb4 = (const float4*)W1c + g * 8 + zf;   // + tap*16

    float4 wA4[7], wB4[7];
    float acc0 = 0.0f, acc1 = 0.0f, acc2 = 0.0f;

#define LDW1(dst, t) {                                                        \
        const float4* p = wb4 + (t) * 16;                                     \
        _Pragma("unroll") for (int i = 0; i < 7; ++i) (dst)[i] = p[i]; }

#define TAP1(t, wreg) {                                                       \
        const int dy = ((t) * 13) >> 6, dx = (t) - dy * 5;                    \
        const float* f = feat + (fbase + dy * 28 + dx) * 12;                  \
        const float4 s0 = *(const float4*)f, s1 = *(const float4*)(f + 4);    \
        const float rr = f[8];                                                \
        const float* w = (const float*)(wreg);                                \
        FMA9(acc0, w, 0); FMA9(acc1, w, 9); FMA9(acc2, w, 18); }

    LDW1(wA4, 0); LDW1(wB4, 1);
    for (int t = 0; t < 24; t += 2) {
        TAP1(t, wA4);     LDW1(wA4, t + 2);       // overread at t=22 -> tap 24/25 ok
        TAP1(t + 1, wB4); LDW1(wB4, t + 3);
    }
    TAP1(24, wA4);   // dy=4,dx=4 folded at compile time? t literal -> yes

    cstage[g * 3 + 0][px] = acc0;
    cstage[g * 3 + 1][px] = acc1;
    cstage[g * 3 + 2][px] = acc2;
    __syncthreads();

    for (int idx = tid; idx < 288; idx += 384) {   // 6 ch * 48 pooled px
        int o = idx / 48, p = idx - o * 48;
        int pr = p / 12, pc = p - pr * 12;
        int cb = (2 * pr) * 24 + 2 * pc;
        float s = cstage[o][cb] + cstage[o][cb + 1] +
                  cstage[o][cb + 24] + cstage[o][cb + 25];
        h1[(img * 6 + o) * 144 + (band * 4 + pr) * 12 + pc] = 0.25f * s;
    }
#undef LDW1
#undef TAP1
}

// ---------------------------------------------------------------------------
// K2: conv2 + pool. Block = 1 image, 256 threads = 4 out-groups (4 ch each,
// wave-uniform) x 64 px.  150-tap loop, 9 float4 weights/tap via VMEM with
// A/B rotation; feat reads are the only lgkm ops -> counted waits.
// ---------------------------------------------------------------------------
__global__ __launch_bounds__(256) void k_conv2(
    const float* __restrict__ h1, const float* __restrict__ W2q,
    const int* __restrict__ zp, float* __restrict__ h2)
{
    __shared__ float feat[864 * 12];
    __shared__ float cstage[64][17];
    const int b = blockIdx.x;
    const int tid = threadIdx.x;
    const float* hb = h1 + b * 864;

    for (int e = tid; e < 864; e += 256) {
        float fr[12];
        spline_feats(hb[e], fr);
        store_feat_row(&feat[e * 12], fr);
    }
    __syncthreads();

    const int zf = (int)tid * zp[0];                 // runtime 0, divergent
    const int g = tid >> 6, px = tid & 63;
    const int y = px >> 3, xc = px & 7;
    const int fbase = y * 12 + xc;
    const float4* wb4 = (const float4*)W2q + g * 10 + zf;  // + tap*40

    float4 wA4[9], wB4[9];
    float acc0 = 0.0f, acc1 = 0.0f, acc2 = 0.0f, acc3 = 0.0f;

#define LDW2(dst, t) {                                                        \
        const float4* p = wb4 + (t) * 40;                                     \
        _Pragma("unroll") for (int i = 0; i < 9; ++i) (dst)[i] = p[i]; }

#define TAP2(t, wreg) {                                                       \
        const int c = ((t) * 41) >> 10;                                       \
        const int r = (t) - c * 25;                                           \
        const int dy = (r * 13) >> 6, dx = r - dy * 5;                        \
        const float* f = feat + (c * 144 + fbase + dy * 12 + dx) * 12;        \
        const float4 s0 = *(const float4*)f, s1 = *(const float4*)(f + 4);    \
        const float rr = f[8];                                                \
        const float* w = (const float*)(wreg);                                \
        FMA9(acc0, w, 0); FMA9(acc1, w, 9); FMA9(acc2, w, 18); FMA9(acc3, w, 27); }

    LDW2(wA4, 0); LDW2(wB4, 1);
    for (int t = 0; t < 150; t += 2) {
        TAP2(t, wA4);     LDW2(wA4, t + 2);    // t=148 -> tap 150 overread (safe, unused)
        TAP2(t + 1, wB4); LDW2(wB4, t + 3);
    }

    cstage[px][g * 4 + 0] = acc0;
    cstage[px][g * 4 + 1] = acc1;
    cstage[px][g * 4 + 2] = acc2;
    cstage[px][g * 4 + 3] = acc3;
    __syncthreads();

    {   // pooled outputs: tid = o*16 + p ; h2 row layout [16][4][4]
        const int o = tid >> 4, p = tid & 15;
        const int py = p >> 2, px2 = p & 3;
        const int cb = (2 * py) * 8 + 2 * px2;
        float s = cstage[cb][o] + cstage[cb + 1][o] +
                  cstage[cb + 8][o] + cstage[cb + 9][o];
        h2[b * 256 + tid] = 0.25f * s;
    }
#undef LDW2
#undef TAP2
}

// ---------------------------------------------------------------------------
// K3: fc1(relu) -> fc2(relu) -> fc3. One block = 4 batch rows, 256 threads.
// ---------------------------------------------------------------------------
__global__ __launch_bounds__(256) void k_fc(
    const float* __restrict__ h2,
    const float* __restrict__ w1, const float* __restrict__ b1,
    const float* __restrict__ w2, const float* __restrict__ b2,
    const float* __restrict__ w3, const float* __restrict__ b3,
    float* __restrict__ out)
{
    __shared__ float xin[4][260];
    __shared__ float a1[4][120];
    __shared__ float a2[4][84];
    const int tid = threadIdx.x;
    const int r0 = blockIdx.x * 4;

    for (int i = tid; i < 1024; i += 256)
        xin[i >> 8][i & 255] = h2[r0 * 256 + i];
    __syncthreads();

    for (int idx = tid; idx < 480; idx += 256) {      // 120 out x 4 rows
        const int o = idx >> 2, r = idx & 3;
        const float* w = w1 + o * 256;
        float s = 0.0f;
#pragma unroll 8
        for (int k = 0; k < 64; ++k) {
            float4 wv = ((const float4*)w)[k];
            float4 xv = *(const float4*)(&xin[r][k * 4]);
            s += wv.x * xv.x + wv.y * xv.y + wv.z * xv.z + wv.w * xv.w;
        }
        a1[r][o] = fmaxf(s + b1[o], 0.0f);
    }
    __syncthreads();

    for (int idx = tid; idx < 336; idx += 256) {      // 84 out x 4 rows
        const int o = idx >> 2, r = idx & 3;
        const float* w = w2 + o * 120;
        float s = 0.0f;
#pragma unroll
        for (int k = 0; k < 30; ++k) {
            float4 wv = ((const float4*)w)[k];
            float4 xv = *(const float4*)(&a1[r][k * 4]);
            s += wv.x * xv.x + wv.y * xv.y + wv.z * xv.z + wv.w * xv.w;
        }
        a2[r][o] = fmaxf(s + b2[o], 0.0f);
    }
    __syncthreads();

    for (int idx = tid; idx < 248; idx += 256) {      // 62 out x 4 rows
        const int o = idx >> 2, r = idx & 3;
        const float* w = w3 + o * 84;
        float s = 0.0f;
#pragma unroll
        for (int k = 0; k < 21; ++k) {
            float4 wv = ((const float4*)w)[k];
            float4 xv = *(const float4*)(&a2[r][k * 4]);
            s += wv.x * xv.x + wv.y * xv.y + wv.z * xv.z + wv.w * xv.w;
        }
        out[(r0 + r) * 62 + o] = s + b3[o];
    }
}

// ---------------------------------------------------------------------------
extern "C" void kernel_launch(void* const* d_in, const int* in_sizes, int n_in,
                              void* d_out, int out_size, void* d_ws, size_t ws_size,
                              hipStream_t stream)
{
    (void)in_sizes; (void)n_in; (void)out_size; (void)ws_size;
    const float* x      = (const float*)d_in[0];
    const float* c1_bw  = (const float*)d_in[1];
    const float* c1_sw  = (const float*)d_in[2];
    const float* c1_sc  = (const float*)d_in[3];
    const float* c2_bw  = (const float*)d_in[4];
    const float* c2_sw  = (const float*)d_in[5];
    const float* c2_sc  = (const float*)d_in[6];
    const float* fc1_w  = (const float*)d_in[7];
    const float* fc1_b  = (const float*)d_in[8];
    const float* fc2_w  = (const float*)d_in[9];
    const float* fc2_b  = (const float*)d_in[10];
    const float* fc3_w  = (const float*)d_in[11];
    const float* fc3_b  = (const float*)d_in[12];
    float* out = (float*)d_out;

    float* ws  = (float*)d_ws;
    float* W1c = ws;                 // 1600   [25][2][32]
    float* W2q = ws + 1600;          // 24000  [600][40]
    int*   zb  = (int*)(ws + 25600); // 16 floats of slack
    float* h1  = ws + 25616;         // 1024*6*144 = 884736
    float* h2  = ws + 910352;        // 1024*256   = 262144

    hipLaunchKernelGGL(k_prep, dim3(94), dim3(256), 0, stream,
                       c1_bw, c1_sw, c1_sc, c2_bw, c2_sw, c2_sc, W1c, W2q, zb);
    hipLaunchKernelGGL(k_conv1, dim3(3072), dim3(384), 0, stream, x, W1c, zb, h1);
    hipLaunchKernelGGL(k_conv2, dim3(1024), dim3(256), 0, stream, h1, W2q, zb, h2);
    hipLaunchKernelGGL(k_fc, dim3(256), dim3(256), 0, stream,
                       h2, fc1_w, fc1_b, fc2_w, fc2_b, fc3_w, fc3_b, out);
}

// Round 4
// 159.903 us; speedup vs baseline: 1.7686x; 1.7686x over previous
//
#include <hip/hip_runtime.h>

// ---------------------------------------------------------------------------
// LeNet5-KAN on MI355X.  R4: weights staged in LDS (broadcast ds_read), thread
// = 2x2 pool-quad x all outs, float2 (v_pk_fma_f32) accumulators paired over
// out-channels, cross-c reduction in conv2 via f32 global atomics.
// Spline: uniform knots => cardinal cubic B-spline closed form.
//   u = 2.5x + 5.5 ; cell i = floor(u), w = u - i
//   nonzero bases j=i-3..i: {(1-w)^3, 3w^3-6w^2+4, -3w^3+3w^2+3w+1, w^3}/6
// Feature row per element (12 floats): f[0..7]=bases, f[8]=relu(x), pad 3.
// ---------------------------------------------------------------------------

typedef float v2f __attribute__((ext_vector_type(2)));

#define ONE_SIXTH 0.16666666666666666f

__device__ __forceinline__ void spline_feats(float v, float* __restrict__ f) {
    float u  = 2.5f * v + 5.5f;
    bool valid = (u >= 0.0f) && (u < 11.0f);
    float fi = floorf(u);
    int   i  = (int)fi;
    float w  = u - fi;
    float omw = 1.0f - w;
    float w2 = w * w, w3 = w2 * w;
    float c0 = omw * omw * omw * ONE_SIXTH;
    float c1 = (3.0f * w3 - 6.0f * w2 + 4.0f) * ONE_SIXTH;
    float c2 = (-3.0f * w3 + 3.0f * w2 + 3.0f * w + 1.0f) * ONE_SIXTH;
    float c3 = w3 * ONE_SIXTH;
    int j0 = i - 3;
#pragma unroll
    for (int j = 0; j < 8; ++j) {
        int d = j - j0;
        float val = (d == 0) ? c0 : (d == 1) ? c1 : (d == 2) ? c2 : (d == 3) ? c3 : 0.0f;
        f[j] = valid ? val : 0.0f;
    }
    f[8] = fmaxf(v, 0.0f);
    f[9] = 0.0f; f[10] = 0.0f; f[11] = 0.0f;
}

__device__ __forceinline__ void st3(float* __restrict__ d, const float* __restrict__ f) {
    *(float4*)(d)     = *(const float4*)(f);
    *(float4*)(d + 4) = *(const float4*)(f + 4);
    *(float4*)(d + 8) = *(const float4*)(f + 8);
}

// compile-time (after unroll) selection of feature k from a loaded row
#define FSEL(a, b, r, k) ((k) == 0 ? (a).x : (k) == 1 ? (a).y : (k) == 2 ? (a).z : \
                          (k) == 3 ? (a).w : (k) == 4 ? (b).x : (k) == 5 ? (b).y : \
                          (k) == 6 ? (b).z : (k) == 7 ? (b).w : (r))

// ---------------------------------------------------------------------------
// K0: repack weights (out-transposed, k-padded to 12) + zero h2.
// W1t[25 tap][12 k][8 o]  (o<6 valid, k<9 valid)
// W2t[6 c][25 tap][12 k][16 o]  (k<9 valid)
// ---------------------------------------------------------------------------
__global__ __launch_bounds__(256) void k_prep(
    const float* __restrict__ c1_bw, const float* __restrict__ c1_sw,
    const float* __restrict__ c1_sc,
    const float* __restrict__ c2_bw, const float* __restrict__ c2_sw,
    const float* __restrict__ c2_sc,
    float* __restrict__ W1t, float* __restrict__ W2t, float* __restrict__ h2)
{
    int t = blockIdx.x * 256 + threadIdx.x;
    if (t < 262144) h2[t] = 0.0f;
    if (t < 2400) {
        int tap = t / 96, r = t - tap * 96;
        int k = r >> 3, o = r & 7;
        float v = 0.0f;
        if (o < 6 && k < 9) {
            int idx = o * 25 + tap;
            v = (k == 8) ? c1_bw[idx] : c1_sw[idx * 8 + k] * c1_sc[idx];
        }
        W1t[t] = v;
    }
    if (t < 28800) {
        int c = t / 4800, r = t - c * 4800;
        int tap = r / 192, rr = r - tap * 192;
        int k = rr >> 4, o = rr & 15;
        float v = 0.0f;
        if (k < 9) {
            int idx = o * 150 + c * 25 + tap;
            v = (k == 8) ? c2_bw[idx] : c2_sw[idx * 8 + k] * c2_sc[idx];
        }
        W2t[t] = v;
    }
}

// ---------------------------------------------------------------------------
// K1: conv1 + pool. Block = (4 images, band of 8 out-rows). 192 threads,
// thread = 2x2 out-px quad x 6 outs (3 float2 pairs). Weights in LDS.
// feat word addr = 4132*m + 344*row + 12*col  (bank-spread pads).
// ---------------------------------------------------------------------------
__global__ __launch_bounds__(192, 1) void k_conv1(
    const float* __restrict__ x, const float* __restrict__ W1t,
    float* __restrict__ h1)
{
    __shared__ float smem[16528 + 2400];
    float* feat = smem;
    float* wsm  = smem + 16528;          // [25][12][8]
    const int blk = blockIdx.x;
    const int i0 = (blk / 3) * 4, band = blk - (blk / 3) * 3;
    const int tid = threadIdx.x;

    for (int e = tid; e < 1344; e += 192) {       // 4 img x 12 rows x 28 cols
        int m = e / 336, r1 = e - m * 336;
        int r = r1 / 28, cc = r1 - r * 28;
        float v = x[(i0 + m) * 784 + (band * 8 + r) * 28 + cc];
        float fr[12]; spline_feats(v, fr);
        st3(feat + 4132 * m + 344 * r + 12 * cc, fr);
    }
    for (int i = tid; i < 600; i += 192)
        ((float4*)wsm)[i] = ((const float4*)W1t)[i];
    __syncthreads();

    const int m = tid / 48, r2 = tid - m * 48;
    const int qy = r2 / 12, qx = r2 - qy * 12;
    const float* fb = feat + 4132 * m + 688 * qy + 24 * qx;
    v2f acc[4][3];
#pragma unroll
    for (int p = 0; p < 4; ++p)
#pragma unroll
        for (int j = 0; j < 3; ++j) acc[p][j] = (v2f){0.0f, 0.0f};

    for (int dy = 0; dy < 5; ++dy) {
        for (int dx = 0; dx < 5; ++dx) {
            const float* f0 = fb + 344 * dy + 12 * dx;
            const float4 a0 = *(const float4*)(f0),       b0 = *(const float4*)(f0 + 4);
            const float4 a1 = *(const float4*)(f0 + 12),  b1 = *(const float4*)(f0 + 16);
            const float4 a2 = *(const float4*)(f0 + 344), b2 = *(const float4*)(f0 + 348);
            const float4 a3 = *(const float4*)(f0 + 356), b3 = *(const float4*)(f0 + 360);
            const float r0 = f0[8], r1 = f0[20], r2v = f0[352], r3 = f0[364];
            const float* wt = wsm + (dy * 5 + dx) * 96;
#pragma unroll
            for (int k = 0; k < 9; ++k) {
                const float4 wa = *(const float4*)(wt + k * 8);
                const v2f   wc = *(const v2f*)(wt + k * 8 + 4);
                const v2f w0 = (v2f){wa.x, wa.y}, w1 = (v2f){wa.z, wa.w};
                const float e0 = FSEL(a0, b0, r0, k), e1 = FSEL(a1, b1, r1, k);
                const float e2 = FSEL(a2, b2, r2v, k), e3 = FSEL(a3, b3, r3, k);
                acc[0][0] += (v2f){e0, e0} * w0; acc[0][1] += (v2f){e0, e0} * w1; acc[0][2] += (v2f){e0, e0} * wc;
                acc[1][0] += (v2f){e1, e1} * w0; acc[1][1] += (v2f){e1, e1} * w1; acc[1][2] += (v2f){e1, e1} * wc;
                acc[2][0] += (v2f){e2, e2} * w0; acc[2][1] += (v2f){e2, e2} * w1; acc[2][2] += (v2f){e2, e2} * wc;
                acc[3][0] += (v2f){e3, e3} * w0; acc[3][1] += (v2f){e3, e3} * w1; acc[3][2] += (v2f){e3, e3} * wc;
            }
        }
    }
    // pool (quad) + store h1[img][6][12][12]
    const int img = i0 + m, row = band * 4 + qy;
#pragma unroll
    for (int j = 0; j < 3; ++j) {
        v2f p = (acc[0][j] + acc[1][j] + acc[2][j] + acc[3][j]) * 0.25f;
        h1[((img * 6 + 2 * j) * 12 + row) * 12 + qx]     = p.x;
        h1[((img * 6 + 2 * j + 1) * 12 + row) * 12 + qx] = p.y;
    }
}

// ---------------------------------------------------------------------------
// K2: conv2 + pool. Block = (8 images, c-slice). 128 threads, thread =
// 2x2 quad x 16 outs (8 float2 pairs). Weights (c-slice) in LDS; cross-c
// reduction via unsafeAtomicAdd into zeroed h2.
// feat word addr = 1828*m + 152*row + 12*col.
// ---------------------------------------------------------------------------
__global__ __launch_bounds__(128, 1) void k_conv2(
    const float* __restrict__ h1, const float* __restrict__ W2t,
    float* __restrict__ h2)
{
    __shared__ float smem[14624 + 4800];
    float* feat = smem;
    float* wsm  = smem + 14624;          // [25][12][16]
    const int blk = blockIdx.x;
    const int g0 = (blk / 6) * 8, c = blk - (blk / 6) * 6;
    const int tid = threadIdx.x;

    for (int e = tid; e < 1152; e += 128) {       // 8 img x 144 elems
        int m = e / 144, r1 = e - m * 144;
        int r = r1 / 12, cc = r1 - r * 12;
        float v = h1[((g0 + m) * 6 + c) * 144 + r1];
        float fr[12]; spline_feats(v, fr);
        st3(feat + 1828 * m + 152 * r + 12 * cc, fr);
    }
    for (int i = tid; i < 1200; i += 128)
        ((float4*)wsm)[i] = ((const float4*)(W2t + c * 4800))[i];
    __syncthreads();

    const int m = tid >> 4, qy = (tid >> 2) & 3, qx = tid & 3;
    const float* fb = feat + 1828 * m + 304 * qy + 24 * qx;
    v2f acc[4][8];
#pragma unroll
    for (int p = 0; p < 4; ++p)
#pragma unroll
        for (int j = 0; j < 8; ++j) acc[p][j] = (v2f){0.0f, 0.0f};

    for (int dy = 0; dy < 5; ++dy) {
        for (int dx = 0; dx < 5; ++dx) {
            const float* f0 = fb + 152 * dy + 12 * dx;
            const float4 a0 = *(const float4*)(f0),       b0 = *(const float4*)(f0 + 4);
            const float4 a1 = *(const float4*)(f0 + 12),  b1 = *(const float4*)(f0 + 16);
            const float4 a2 = *(const float4*)(f0 + 152), b2 = *(const float4*)(f0 + 156);
            const float4 a3 = *(const float4*)(f0 + 164), b3 = *(const float4*)(f0 + 168);
            const float r0 = f0[8], r1 = f0[20], r2v = f0[160], r3 = f0[172];
            const float* wt = wsm + (dy * 5 + dx) * 192;
#pragma unroll
            for (int k = 0; k < 9; ++k) {
                const float4 wa = *(const float4*)(wt + k * 16);
                const float4 wb = *(const float4*)(wt + k * 16 + 4);
                const float4 wc = *(const float4*)(wt + k * 16 + 8);
                const float4 wd = *(const float4*)(wt + k * 16 + 12);
                const v2f w[8] = {(v2f){wa.x, wa.y}, (v2f){wa.z, wa.w},
                                  (v2f){wb.x, wb.y}, (v2f){wb.z, wb.w},
                                  (v2f){wc.x, wc.y}, (v2f){wc.z, wc.w},
                                  (v2f){wd.x, wd.y}, (v2f){wd.z, wd.w}};
                const float e0 = FSEL(a0, b0, r0, k), e1 = FSEL(a1, b1, r1, k);
                const float e2 = FSEL(a2, b2, r2v, k), e3 = FSEL(a3, b3, r3, k);
#pragma unroll
                for (int j = 0; j < 8; ++j) {
                    acc[0][j] += (v2f){e0, e0} * w[j];
                    acc[1][j] += (v2f){e1, e1} * w[j];
                    acc[2][j] += (v2f){e2, e2} * w[j];
                    acc[3][j] += (v2f){e3, e3} * w[j];
                }
            }
        }
    }
    // pool quad, atomic-accumulate into h2[img][16 o][4][4]
    float* hp = h2 + (g0 + m) * 256 + qy * 4 + qx;
#pragma unroll
    for (int j = 0; j < 8; ++j) {
        v2f p = (acc[0][j] + acc[1][j] + acc[2][j] + acc[3][j]) * 0.25f;
        unsafeAtomicAdd(hp + (2 * j) * 16, p.x);
        unsafeAtomicAdd(hp + (2 * j + 1) * 16, p.y);
    }
}

// ---------------------------------------------------------------------------
// K3: fc1(relu) -> fc2(relu) -> fc3. One block = 4 batch rows, 256 threads.
// ---------------------------------------------------------------------------
__global__ __launch_bounds__(256) void k_fc(
    const float* __restrict__ h2,
    const float* __restrict__ w1, const float* __restrict__ b1,
    const float* __restrict__ w2, const float* __restrict__ b2,
    const float* __restrict__ w3, const float* __restrict__ b3,
    float* __restrict__ out)
{
    __shared__ float xin[4][260];
    __shared__ float a1[4][120];
    __shared__ float a2[4][84];
    const int tid = threadIdx.x;
    const int r0 = blockIdx.x * 4;

    for (int i = tid; i < 1024; i += 256)
        xin[i >> 8][i & 255] = h2[r0 * 256 + i];
    __syncthreads();

    for (int idx = tid; idx < 480; idx += 256) {
        const int o = idx >> 2, r = idx & 3;
        const float* w = w1 + o * 256;
        float s = 0.0f;
#pragma unroll 8
        for (int k = 0; k < 64; ++k) {
            float4 wv = ((const float4*)w)[k];
            float4 xv = *(const float4*)(&xin[r][k * 4]);
            s += wv.x * xv.x + wv.y * xv.y + wv.z * xv.z + wv.w * xv.w;
        }
        a1[r][o] = fmaxf(s + b1[o], 0.0f);
    }
    __syncthreads();

    for (int idx = tid; idx < 336; idx += 256) {
        const int o = idx >> 2, r = idx & 3;
        const float* w = w2 + o * 120;
        float s = 0.0f;
#pragma unroll
        for (int k = 0; k < 30; ++k) {
            float4 wv = ((const float4*)w)[k];
            float4 xv = *(const float4*)(&a1[r][k * 4]);
            s += wv.x * xv.x + wv.y * xv.y + wv.z * xv.z + wv.w * xv.w;
        }
        a2[r][o] = fmaxf(s + b2[o], 0.0f);
    }
    __syncthreads();

    for (int idx = tid; idx < 248; idx += 256) {
        const int o = idx >> 2, r = idx & 3;
        const float* w = w3 + o * 84;
        float s = 0.0f;
#pragma unroll
        for (int k = 0; k < 21; ++k) {
            float4 wv = ((const float4*)w)[k];
            float4 xv = *(const float4*)(&a2[r][k * 4]);
            s += wv.x * xv.x + wv.y * xv.y + wv.z * xv.z + wv.w * xv.w;
        }
        out[(r0 + r) * 62 + o] = s + b3[o];
    }
}

// ---------------------------------------------------------------------------
extern "C" void kernel_launch(void* const* d_in, const int* in_sizes, int n_in,
                              void* d_out, int out_size, void* d_ws, size_t ws_size,
                              hipStream_t stream)
{
    (void)in_sizes; (void)n_in; (void)out_size; (void)ws_size;
    const float* x      = (const float*)d_in[0];
    const float* c1_bw  = (const float*)d_in[1];
    const float* c1_sw  = (const float*)d_in[2];
    const float* c1_sc  = (const float*)d_in[3];
    const float* c2_bw  = (const float*)d_in[4];
    const float* c2_sw  = (const float*)d_in[5];
    const float* c2_sc  = (const float*)d_in[6];
    const float* fc1_w  = (const float*)d_in[7];
    const float* fc1_b  = (const float*)d_in[8];
    const float* fc2_w  = (const float*)d_in[9];
    const float* fc2_b  = (const float*)d_in[10];
    const float* fc3_w  = (const float*)d_in[11];
    const float* fc3_b  = (const float*)d_in[12];
    float* out = (float*)d_out;

    float* ws  = (float*)d_ws;
    float* W1t = ws;                  // 2400
    float* W2t = ws + 2400;           // 28800
    float* h1  = ws + 31200;          // 1024*6*144 = 884736
    float* h2  = ws + 915936;         // 1024*256   = 262144

    hipLaunchKernelGGL(k_prep, dim3(1024), dim3(256), 0, stream,
                       c1_bw, c1_sw, c1_sc, c2_bw, c2_sw, c2_sc, W1t, W2t, h2);
    hipLaunchKernelGGL(k_conv1, dim3(768), dim3(192), 0, stream, x, W1t, h1);
    hipLaunchKernelGGL(k_conv2, dim3(768), dim3(128), 0, stream, h1, W2t, h2);
    hipLaunchKernelGGL(k_fc, dim3(256), dim3(256), 0, stream,
                       h2, fc1_w, fc1_b, fc2_w, fc2_b, fc3_w, fc3_b, out);
}

// Round 5
// 124.919 us; speedup vs baseline: 2.2639x; 1.2801x over previous
//
#include <hip/hip_runtime.h>
#include <hip/hip_fp16.h>

// ---------------------------------------------------------------------------
// LeNet5-KAN on MI355X.  R5: f16 operand compression everywhere.
//  - features: 8 spline bases packed f16x8 (one uint4 -> one ds_read_b128),
//    relu stored as separate f16 -> halves LDS footprint and DS traffic.
//  - weights: f16 o-pairs in LDS, wave-uniform broadcast b128 reads,
//    cvt to f32 pairs, accumulate with v_pk_fma_f32 (fp32 exact accum).
//  - thread owns 8 px (conv1) / 4 px x 16 outs (conv2) so one weight read
//    feeds 24-32 pk-FMAs (DS:VALU ratio ~1:4 per CU).
//  - odd strides (29/813, 13/157) spread b128 lanes over all 8 bank-quads.
// Spline: uniform knots => cardinal cubic B-spline closed form.
// ---------------------------------------------------------------------------

typedef float v2f __attribute__((ext_vector_type(2)));

#define ONE_SIXTH 0.16666666666666666f

__device__ __forceinline__ unsigned int pk2h(float a, float b) {
    __half2 h = __float22half2_rn(make_float2(a, b));
    return *reinterpret_cast<unsigned int*>(&h);
}
__device__ __forceinline__ v2f up2h(unsigned int u) {
    __half2 h = *reinterpret_cast<__half2*>(&u);
    float2 f = __half22float2(h);
    return (v2f){f.x, f.y};
}

__device__ __forceinline__ void spline9(float v, float* __restrict__ f) {
    float u  = 2.5f * v + 5.5f;
    bool valid = (u >= 0.0f) && (u < 11.0f);
    float fi = floorf(u);
    int   i  = (int)fi;
    float w  = u - fi;
    float omw = 1.0f - w;
    float w2 = w * w, w3 = w2 * w;
    float c0 = omw * omw * omw * ONE_SIXTH;
    float c1 = (3.0f * w3 - 6.0f * w2 + 4.0f) * ONE_SIXTH;
    float c2 = (-3.0f * w3 + 3.0f * w2 + 3.0f * w + 1.0f) * ONE_SIXTH;
    float c3 = w3 * ONE_SIXTH;
    int j0 = i - 3;
#pragma unroll
    for (int j = 0; j < 8; ++j) {
        int d = j - j0;
        float val = (d == 0) ? c0 : (d == 1) ? c1 : (d == 2) ? c2 : (d == 3) ? c3 : 0.0f;
        f[j] = valid ? val : 0.0f;
    }
    f[8] = fmaxf(v, 0.0f);
}

__device__ __forceinline__ void spline_pack(float v, uint4& a, __half& r) {
    float f[9];
    spline9(v, f);
    a.x = pk2h(f[0], f[1]); a.y = pk2h(f[2], f[3]);
    a.z = pk2h(f[4], f[5]); a.w = pk2h(f[6], f[7]);
    r = __float2half(f[8]);
}

// ---------------------------------------------------------------------------
// K0: repack weights to f16 o-pairs + zero h2.
// W1h[tap][k][4dw]: dw pd<3 = halves {w[2pd], w[2pd+1]} (6 outs), pd3 = 0.
// W2h[c][tap][k][8dw]: dw pd = halves {w[2pd], w[2pd+1]} (16 outs).
// ---------------------------------------------------------------------------
__global__ __launch_bounds__(256) void k_prep(
    const float* __restrict__ c1_bw, const float* __restrict__ c1_sw,
    const float* __restrict__ c1_sc,
    const float* __restrict__ c2_bw, const float* __restrict__ c2_sw,
    const float* __restrict__ c2_sc,
    unsigned int* __restrict__ W1h, unsigned int* __restrict__ W2h,
    float* __restrict__ h2)
{
    int t = blockIdx.x * 256 + threadIdx.x;
    if (t < 262144) h2[t] = 0.0f;
    if (t < 900) {                       // (tap*9 + k)*4 + pd
        int q = t >> 2, pd = t & 3;
        int tap = q / 9, k = q - tap * 9;
        unsigned int v = 0u;
        if (pd < 3) {
            int o0 = 2 * pd, o1 = o0 + 1;
            int i0 = o0 * 25 + tap, i1 = o1 * 25 + tap;
            float a = (k == 8) ? c1_bw[i0] : c1_sw[i0 * 8 + k] * c1_sc[i0];
            float b = (k == 8) ? c1_bw[i1] : c1_sw[i1 * 8 + k] * c1_sc[i1];
            v = pk2h(a, b);
        }
        W1h[t] = v;
    }
    if (t < 10800) {                     // ((c*25+tap)*9 + k)*8 + pd
        int q = t >> 3, pd = t & 7;
        int k = q % 9, ct = q / 9;       // ct = c*25 + tap
        int o0 = 2 * pd, o1 = o0 + 1;
        int i0 = o0 * 150 + ct, i1 = o1 * 150 + ct;
        float a = (k == 8) ? c2_bw[i0] : c2_sw[i0 * 8 + k] * c2_sc[i0];
        float b = (k == 8) ? c2_bw[i1] : c2_sw[i1 * 8 + k] * c2_sc[i1];
        W2h[t] = pk2h(a, b);
    }
}

// ---------------------------------------------------------------------------
// K1: conv1 + pool. Block = 2 images, 192 threads. Thread = 2x4 conv px
// (-> 1x2 pooled px) x 6 outs (3 f32-pairs). Rolled 25-tap loop.
// A addr: m*813 + row*29 + col (odd strides -> 8 bank-quads).
// ---------------------------------------------------------------------------
__global__ __launch_bounds__(192, 2) void k_conv1(
    const float* __restrict__ x, const unsigned int* __restrict__ W1h,
    float* __restrict__ h1)
{
    __shared__ uint4  Ab[1626];    // 2*813
    __shared__ __half Rb[1632];
    __shared__ uint4  Wb[225];     // [25 tap][9 k] of 4 dw
    const int i0 = blockIdx.x * 2;
    const int tid = threadIdx.x;

    for (int e = tid; e < 1568; e += 192) {
        int m = e / 784, p = e - m * 784;
        int r = p / 28, cc = p - r * 28;
        uint4 a; __half rh;
        spline_pack(x[(i0 + m) * 784 + p], a, rh);
        int ai = m * 813 + r * 29 + cc;
        Ab[ai] = a;
        Rb[m * 816 + r * 29 + cc] = rh;
    }
    for (int i = tid; i < 225; i += 192)
        Wb[i] = ((const uint4*)W1h)[i];
    __syncthreads();

    if (tid < 144) {
        const int mm = tid / 72, t = tid - mm * 72;
        const int ry = t / 6, cx = t - ry * 6;
        const int row0 = 2 * ry, col0 = 4 * cx;
        const int abase = mm * 813 + row0 * 29 + col0;
        const int rbase = mm * 816 + row0 * 29 + col0;

        v2f acc[2][4][3];
#pragma unroll
        for (int oy = 0; oy < 2; ++oy)
#pragma unroll
            for (int ox = 0; ox < 4; ++ox)
#pragma unroll
                for (int j = 0; j < 3; ++j) acc[oy][ox][j] = (v2f){0.0f, 0.0f};

        for (int dy = 0; dy < 5; ++dy) {
            for (int dx = 0; dx < 5; ++dx) {
                const int tap = dy * 5 + dx;
                v2f w[9][3];
#pragma unroll
                for (int k = 0; k < 9; ++k) {
                    uint4 wv = Wb[tap * 9 + k];
                    w[k][0] = up2h(wv.x); w[k][1] = up2h(wv.y); w[k][2] = up2h(wv.z);
                }
#pragma unroll
                for (int oy = 0; oy < 2; ++oy) {
#pragma unroll
                    for (int ox = 0; ox < 4; ++ox) {
                        const int off = (oy + dy) * 29 + (ox + dx);
                        uint4 av = Ab[abase + off];
                        float e[9];
                        v2f f2;
                        f2 = up2h(av.x); e[0] = f2.x; e[1] = f2.y;
                        f2 = up2h(av.y); e[2] = f2.x; e[3] = f2.y;
                        f2 = up2h(av.z); e[4] = f2.x; e[5] = f2.y;
                        f2 = up2h(av.w); e[6] = f2.x; e[7] = f2.y;
                        e[8] = __half2float(Rb[rbase + off]);
#pragma unroll
                        for (int k = 0; k < 9; ++k) {
                            v2f ee = (v2f){e[k], e[k]};
                            acc[oy][ox][0] += ee * w[k][0];
                            acc[oy][ox][1] += ee * w[k][1];
                            acc[oy][ox][2] += ee * w[k][2];
                        }
                    }
                }
            }
        }
        // pool 2x2 -> pooled row ry, pooled cols 2cx, 2cx+1
#pragma unroll
        for (int j = 0; j < 3; ++j) {
#pragma unroll
            for (int pc = 0; pc < 2; ++pc) {
                v2f p = (acc[0][2 * pc][j] + acc[0][2 * pc + 1][j] +
                         acc[1][2 * pc][j] + acc[1][2 * pc + 1][j]) * 0.25f;
                int base = (i0 + mm) * 864 + ry * 12 + (2 * cx + pc);
                h1[base + (2 * j) * 144]     = p.x;
                h1[base + (2 * j + 1) * 144] = p.y;
            }
        }
    }
}

// ---------------------------------------------------------------------------
// K2: conv2 + pool. Block = (16 images, input channel c). 256 threads,
// thread = 2x2 conv quad (-> 1 pooled px) x 16 outs (8 f32-pairs).
// Cross-c reduction via unsafeAtomicAdd into zeroed h2.
// A addr: m*157 + row*13 + col.
// ---------------------------------------------------------------------------
__global__ __launch_bounds__(256, 2) void k_conv2(
    const float* __restrict__ h1, const unsigned int* __restrict__ W2h,
    float* __restrict__ h2)
{
    __shared__ uint4  A2[2512];    // 16*157
    __shared__ __half R2[2512];
    __shared__ uint4  Wc[450];     // [25 tap][9 k] of 8 dw
    const int blk = blockIdx.x;
    const int g0 = (blk / 6) * 16, c = blk - (blk / 6) * 6;
    const int tid = threadIdx.x;

    for (int e = tid; e < 2304; e += 256) {
        int m = e / 144, p = e - m * 144;
        int r = p / 12, cc = p - r * 12;
        uint4 a; __half rh;
        spline_pack(h1[(g0 + m) * 864 + c * 144 + p], a, rh);
        int ai = m * 157 + r * 13 + cc;
        A2[ai] = a;
        R2[ai] = rh;
    }
    for (int i = tid; i < 450; i += 256)
        Wc[i] = ((const uint4*)(W2h + c * 1800))[i];
    __syncthreads();

    const int mm = tid >> 4, q = tid & 15;
    const int qy = q >> 2, qx = q & 3;
    const int abase = mm * 157 + (2 * qy) * 13 + 2 * qx;

    v2f acc[2][2][8];
#pragma unroll
    for (int oy = 0; oy < 2; ++oy)
#pragma unroll
        for (int ox = 0; ox < 2; ++ox)
#pragma unroll
            for (int j = 0; j < 8; ++j) acc[oy][ox][j] = (v2f){0.0f, 0.0f};

    for (int dy = 0; dy < 5; ++dy) {
        for (int dx = 0; dx < 5; ++dx) {
            const int tap = dy * 5 + dx;
            float e[2][2][9];
#pragma unroll
            for (int oy = 0; oy < 2; ++oy) {
#pragma unroll
                for (int ox = 0; ox < 2; ++ox) {
                    const int ai = abase + (oy + dy) * 13 + (ox + dx);
                    uint4 av = A2[ai];
                    v2f f2;
                    f2 = up2h(av.x); e[oy][ox][0] = f2.x; e[oy][ox][1] = f2.y;
                    f2 = up2h(av.y); e[oy][ox][2] = f2.x; e[oy][ox][3] = f2.y;
                    f2 = up2h(av.z); e[oy][ox][4] = f2.x; e[oy][ox][5] = f2.y;
                    f2 = up2h(av.w); e[oy][ox][6] = f2.x; e[oy][ox][7] = f2.y;
                    e[oy][ox][8] = __half2float(R2[ai]);
                }
            }
#pragma unroll
            for (int k = 0; k < 9; ++k) {
                uint4 wv0 = Wc[(tap * 9 + k) * 2];
                uint4 wv1 = Wc[(tap * 9 + k) * 2 + 1];
                v2f w[8];
                w[0] = up2h(wv0.x); w[1] = up2h(wv0.y);
                w[2] = up2h(wv0.z); w[3] = up2h(wv0.w);
                w[4] = up2h(wv1.x); w[5] = up2h(wv1.y);
                w[6] = up2h(wv1.z); w[7] = up2h(wv1.w);
#pragma unroll
                for (int oy = 0; oy < 2; ++oy) {
#pragma unroll
                    for (int ox = 0; ox < 2; ++ox) {
                        v2f ee = (v2f){e[oy][ox][k], e[oy][ox][k]};
#pragma unroll
                        for (int j = 0; j < 8; ++j)
                            acc[oy][ox][j] += ee * w[j];
                    }
                }
            }
        }
    }
    // pool quad -> pooled px (qy,qx); atomic-accumulate over c
    float* hp = h2 + (g0 + mm) * 256 + qy * 4 + qx;
#pragma unroll
    for (int j = 0; j < 8; ++j) {
        v2f p = (acc[0][0][j] + acc[0][1][j] + acc[1][0][j] + acc[1][1][j]) * 0.25f;
        unsafeAtomicAdd(hp + (2 * j) * 16, p.x);
        unsafeAtomicAdd(hp + (2 * j + 1) * 16, p.y);
    }
}

// ---------------------------------------------------------------------------
// K3: fc1(relu) -> fc2(relu) -> fc3. One block = 4 batch rows, 256 threads.
// ---------------------------------------------------------------------------
__global__ __launch_bounds__(256) void k_fc(
    const float* __restrict__ h2,
    const float* __restrict__ w1, const float* __restrict__ b1,
    const float* __restrict__ w2, const float* __restrict__ b2,
    const float* __restrict__ w3, const float* __restrict__ b3,
    float* __restrict__ out)
{
    __shared__ float xin[4][260];
    __shared__ float a1[4][120];
    __shared__ float a2[4][84];
    const int tid = threadIdx.x;
    const int r0 = blockIdx.x * 4;

    for (int i = tid; i < 1024; i += 256)
        xin[i >> 8][i & 255] = h2[r0 * 256 + i];
    __syncthreads();

    for (int idx = tid; idx < 480; idx += 256) {
        const int o = idx >> 2, r = idx & 3;
        const float* w = w1 + o * 256;
        float s = 0.0f;
#pragma unroll 8
        for (int k = 0; k < 64; ++k) {
            float4 wv = ((const float4*)w)[k];
            float4 xv = *(const float4*)(&xin[r][k * 4]);
            s += wv.x * xv.x + wv.y * xv.y + wv.z * xv.z + wv.w * xv.w;
        }
        a1[r][o] = fmaxf(s + b1[o], 0.0f);
    }
    __syncthreads();

    for (int idx = tid; idx < 336; idx += 256) {
        const int o = idx >> 2, r = idx & 3;
        const float* w = w2 + o * 120;
        float s = 0.0f;
#pragma unroll
        for (int k = 0; k < 30; ++k) {
            float4 wv = ((const float4*)w)[k];
            float4 xv = *(const float4*)(&a1[r][k * 4]);
            s += wv.x * xv.x + wv.y * xv.y + wv.z * xv.z + wv.w * xv.w;
        }
        a2[r][o] = fmaxf(s + b2[o], 0.0f);
    }
    __syncthreads();

    for (int idx = tid; idx < 248; idx += 256) {
        const int o = idx >> 2, r = idx & 3;
        const float* w = w3 + o * 84;
        float s = 0.0f;
#pragma unroll
        for (int k = 0; k < 21; ++k) {
            float4 wv = ((const float4*)w)[k];
            float4 xv = *(const float4*)(&a2[r][k * 4]);
            s += wv.x * xv.x + wv.y * xv.y + wv.z * xv.z + wv.w * xv.w;
        }
        out[(r0 + r) * 62 + o] = s + b3[o];
    }
}

// ---------------------------------------------------------------------------
extern "C" void kernel_launch(void* const* d_in, const int* in_sizes, int n_in,
                              void* d_out, int out_size, void* d_ws, size_t ws_size,
                              hipStream_t stream)
{
    (void)in_sizes; (void)n_in; (void)out_size; (void)ws_size;
    const float* x      = (const float*)d_in[0];
    const float* c1_bw  = (const float*)d_in[1];
    const float* c1_sw  = (const float*)d_in[2];
    const float* c1_sc  = (const float*)d_in[3];
    const float* c2_bw  = (const float*)d_in[4];
    const float* c2_sw  = (const float*)d_in[5];
    const float* c2_sc  = (const float*)d_in[6];
    const float* fc1_w  = (const float*)d_in[7];
    const float* fc1_b  = (const float*)d_in[8];
    const float* fc2_w  = (const float*)d_in[9];
    const float* fc2_b  = (const float*)d_in[10];
    const float* fc3_w  = (const float*)d_in[11];
    const float* fc3_b  = (const float*)d_in[12];
    float* out = (float*)d_out;

    float* ws = (float*)d_ws;
    unsigned int* W1h = (unsigned int*)ws;            // 900 dw  @0
    unsigned int* W2h = (unsigned int*)(ws + 1024);   // 10800 dw @1024
    float* h1 = ws + 16384;                           // 1024*864 = 884736
    float* h2 = ws + 16384 + 884736;                  // 1024*256 = 262144

    hipLaunchKernelGGL(k_prep, dim3(1024), dim3(256), 0, stream,
                       c1_bw, c1_sw, c1_sc, c2_bw, c2_sw, c2_sc, W1h, W2h, h2);
    hipLaunchKernelGGL(k_conv1, dim3(512), dim3(192), 0, stream, x, W1h, h1);
    hipLaunchKernelGGL(k_conv2, dim3(384), dim3(256), 0, stream, h1, W2h, h2);
    hipLaunchKernelGGL(k_fc, dim3(256), dim3(256), 0, stream,
                       h2, fc1_w, fc1_b, fc2_w, fc2_b, fc3_w, fc3_b, out);
}

// Round 6
// 51.559 us; speedup vs baseline: 5.4849x; 2.4228x over previous
//
#include <hip/hip_runtime.h>

// ---------------------------------------------------------------------------
// LeNet5-KAN on MI355X.  R6: MFMA (f16 in, f32 accum) + pool folded into
// weights (pool o conv5x5 == stride-2 conv6x6 with averaged taps).
//
// GEMM view per conv:  out[p][o] = sum_K feat16[elem(p,tap)][k] * W[tap,k][o]
//   K = taps(36) x kpad(16): k0..7 = cubic B-spline bases, k8 = relu, rest 0.
//   A-frag: lane&15 = out px, lane>>4 = k-group (tap half-pair, 16B ds_read)
//   B-frag: lane&15 = o,     lane>>4 = same k-group (16B global load, L2)
//   C     : col = lane&15 (o), row = (lane>>4)*4 + reg  (m89-verified)
// A and B use the identical (group,elem)->k map, so the MFMA-internal k
// permutation is irrelevant (sum over k is permutation invariant).
//
// feat LDS chunks (16B) are XOR-swizzled: ch ^= (ch>>3)&7  (bijective per
// 8-chunk group; spreads the px-stride-2 read pattern to ~2-way = free).
// ---------------------------------------------------------------------------

typedef _Float16 f16;
typedef f16 f16x8 __attribute__((ext_vector_type(8)));
typedef float f32x4 __attribute__((ext_vector_type(4)));

#define ONE_SIXTH 0.16666666666666666f

__device__ __forceinline__ void spline9(float v, float* __restrict__ f) {
    float u  = 2.5f * v + 5.5f;
    bool valid = (u >= 0.0f) && (u < 11.0f);
    float fi = floorf(u);
    int   i  = (int)fi;
    float w  = u - fi;
    float omw = 1.0f - w;
    float w2 = w * w, w3 = w2 * w;
    float c0 = omw * omw * omw * ONE_SIXTH;
    float c1 = (3.0f * w3 - 6.0f * w2 + 4.0f) * ONE_SIXTH;
    float c2 = (-3.0f * w3 + 3.0f * w2 + 3.0f * w + 1.0f) * ONE_SIXTH;
    float c3 = w3 * ONE_SIXTH;
    int j0 = i - 3;
#pragma unroll
    for (int j = 0; j < 8; ++j) {
        int d = j - j0;
        float val = (d == 0) ? c0 : (d == 1) ? c1 : (d == 2) ? c2 : (d == 3) ? c3 : 0.0f;
        f[j] = valid ? val : 0.0f;
    }
    f[8] = fmaxf(v, 0.0f);
}

// two 16B chunks: c0 = bases[0..7] as f16, c1 = {relu, 0,0,0,0,0,0,0}
__device__ __forceinline__ void spline_chunks(float v, uint4& u0, uint4& u1) {
    float f[9];
    spline9(v, f);
    union { f16 h[8]; uint4 u; } a, b;
#pragma unroll
    for (int j = 0; j < 8; ++j) a.h[j] = (f16)f[j];
    b.u.x = 0u; b.u.y = 0u; b.u.z = 0u; b.u.w = 0u;
    b.h[0] = (f16)f[8];
    u0 = a.u; u1 = b.u;
}

// ---------------------------------------------------------------------------
// K0: build pooled-conv weights, f16.
// W1g[(tap*16 + o)*16 + k], tap<36 (6x6), o<16 (6 valid), k<16 (9 valid)
// W2g[((c*36 + tap)*16 + o)*16 + k], c<6, o<16 (all valid), k<16 (9 valid)
// w'[ey][ex] = 0.25 * sum_{a,b in {0,1}, 0<=ey-a<5, 0<=ex-b<5} w[ey-a][ex-b]
// ---------------------------------------------------------------------------
__global__ __launch_bounds__(256) void k_prep(
    const float* __restrict__ c1_bw, const float* __restrict__ c1_sw,
    const float* __restrict__ c1_sc,
    const float* __restrict__ c2_bw, const float* __restrict__ c2_sw,
    const float* __restrict__ c2_sc,
    f16* __restrict__ W1g, f16* __restrict__ W2g)
{
    int t = blockIdx.x * 256 + threadIdx.x;
    if (t < 9216) {
        int tap = t >> 8, r = t & 255;
        int o = r >> 4, k = r & 15;
        float val = 0.0f;
        if (o < 6 && k < 9) {
            int ey = tap / 6, ex = tap - 6 * ey;
            float s = 0.0f;
            for (int a = 0; a < 2; ++a) {
                for (int b = 0; b < 2; ++b) {
                    int dy = ey - a, dx = ex - b;
                    if (dy >= 0 && dy < 5 && dx >= 0 && dx < 5) {
                        int idx = o * 25 + dy * 5 + dx;
                        s += (k == 8) ? c1_bw[idx] : c1_sw[idx * 8 + k] * c1_sc[idx];
                    }
                }
            }
            val = 0.25f * s;
        }
        W1g[t] = (f16)val;
    }
    if (t < 55296) {
        int c = t / 9216, r = t - c * 9216;
        int tap = r >> 8, rr = r & 255;
        int o = rr >> 4, k = rr & 15;
        float val = 0.0f;
        if (k < 9) {
            int ey = tap / 6, ex = tap - 6 * ey;
            float s = 0.0f;
            for (int a = 0; a < 2; ++a) {
                for (int b = 0; b < 2; ++b) {
                    int dy = ey - a, dx = ex - b;
                    if (dy >= 0 && dy < 5 && dx >= 0 && dx < 5) {
                        int idx = o * 150 + c * 25 + dy * 5 + dx;
                        s += (k == 8) ? c2_bw[idx] : c2_sw[idx * 8 + k] * c2_sc[idx];
                    }
                }
            }
            val = 0.25f * s;
        }
        W2g[t] = (f16)val;
    }
}

// ---------------------------------------------------------------------------
// K1: conv1 (fused pool). Block = 1 image, 192 threads = 3 waves.
// M = 144 pooled px (9 tiles of 16, 3 per wave), K = 36 taps x 16 = 18 chunks,
// N = 16 (6 valid outs). Output h1[img][o][144] f32.
// ---------------------------------------------------------------------------
__global__ __launch_bounds__(192, 4) void k_conv1(
    const float* __restrict__ x, const f16* __restrict__ W1g,
    float* __restrict__ h1)
{
    __shared__ uint4 feat[1568];       // 784 elems x 2 chunks, swizzled
    const int img = blockIdx.x;
    const int tid = threadIdx.x;

    for (int e = tid; e < 784; e += 192) {
        uint4 u0, u1;
        spline_chunks(x[img * 784 + e], u0, u1);
        int ch = e * 2;
        int q = (ch >> 3) & 7;
        feat[ch ^ q] = u0;
        feat[(ch + 1) ^ q] = u1;
    }
    __syncthreads();

    const int lane = tid & 63, wv = tid >> 6;
    const int ln15 = lane & 15, g = lane >> 4;
    const int gh = g & 1, gt = g >> 1;

    int ebase[3];
#pragma unroll
    for (int t = 0; t < 3; ++t) {
        int p = (wv * 3 + t) * 16 + ln15;
        int py = p / 12, px = p - py * 12;
        ebase[t] = py * 56 + px * 2;           // (2py)*28 + 2px
    }

    const f16* bptr = W1g + (gt * 16 + ln15) * 16 + gh * 8;  // + kc*512
    f16x8 bfrag = *(const f16x8*)bptr;

    f32x4 acc[3] = {{0,0,0,0},{0,0,0,0},{0,0,0,0}};

    for (int kc = 0; kc < 18; ++kc) {
        int tap = kc * 2 + gt;
        int ey = (tap * 171) >> 10, ex = tap - ey * 6;
        int eoff = ey * 28 + ex;
        f16x8 bcur = bfrag;
        bptr += 512;
        bfrag = *(const f16x8*)bptr;           // 1-deep prefetch (overreads 16B
                                               // into W2g region on last iter)
#pragma unroll
        for (int t = 0; t < 3; ++t) {
            int ch = (ebase[t] + eoff) * 2 + gh;
            ch ^= (ch >> 3) & 7;
            f16x8 afrag = *(const f16x8*)(&feat[ch]);
            acc[t] = __builtin_amdgcn_mfma_f32_16x16x32_f16(afrag, bcur, acc[t], 0, 0, 0);
        }
    }

    if (ln15 < 6) {
#pragma unroll
        for (int t = 0; t < 3; ++t) {
            int p0 = (wv * 3 + t) * 16 + g * 4;    // row = g*4 + reg
            *(float4*)&h1[(img * 6 + ln15) * 144 + p0] =
                make_float4(acc[t][0], acc[t][1], acc[t][2], acc[t][3]);
        }
    }
}

// ---------------------------------------------------------------------------
// K2: conv2 (fused pool). Block = 2 images, 256 threads = 4 waves.
// Per image: M = 16 px (1 tile), K = 6c x 36tap x 16 = 108 chunks, N = 16.
// Wave pair splits K by c (0-2 / 3-5); partial C reduced via LDS.
// Output h2[img][o*16 + p] f32 (matches fc reshape order).
// ---------------------------------------------------------------------------
__global__ __launch_bounds__(256, 2) void k_conv2(
    const float* __restrict__ h1, const f16* __restrict__ W2g,
    float* __restrict__ h2)
{
    __shared__ uint4 feat[3456];       // 2 img x 864 elems x 2 chunks
    __shared__ float4 rbuf[2][64];
    const int i0 = blockIdx.x * 2;
    const int tid = threadIdx.x;

    for (int e = tid; e < 1728; e += 256) {
        int im = e / 864, r = e - im * 864;
        uint4 u0, u1;
        spline_chunks(h1[(i0 + im) * 864 + r], u0, u1);
        int ch = r * 2;
        int q = (ch >> 3) & 7;
        int b = im * 1728;
        feat[b + (ch ^ q)] = u0;
        feat[b + ((ch + 1) ^ q)] = u1;
    }
    __syncthreads();

    const int lane = tid & 63, wv = tid >> 6;
    const int im = wv >> 1, chalf = wv & 1;
    const int ln15 = lane & 15, g = lane >> 4;
    const int gh = g & 1, gt = g >> 1;
    const int py = ln15 >> 2, px = ln15 & 3;
    const int epx = py * 24 + px * 2;          // (2py)*12 + 2px
    const int fb = im * 1728;

    const f16* bptr = W2g + ((chalf * 3 * 36 + gt) * 16 + ln15) * 16 + gh * 8;
    f16x8 bfrag = *(const f16x8*)bptr;

    f32x4 acc = {0, 0, 0, 0};

    for (int cc = 0; cc < 3; ++cc) {
        const int cbase = (chalf * 3 + cc) * 144;
        for (int tk = 0; tk < 18; ++tk) {
            int tap = tk * 2 + gt;
            int ey = (tap * 171) >> 10, ex = tap - ey * 6;
            f16x8 bcur = bfrag;
            bptr += 512;                        // 2 taps x 256 halfs
            bfrag = *(const f16x8*)bptr;        // overread-safe (h1 follows)
            int elem = cbase + epx + ey * 12 + ex;
            int ch = elem * 2 + gh;
            ch ^= (ch >> 3) & 7;
            f16x8 afrag = *(const f16x8*)(&feat[fb + ch]);
            acc = __builtin_amdgcn_mfma_f32_16x16x32_f16(afrag, bcur, acc, 0, 0, 0);
        }
    }

    if (chalf) rbuf[im][lane] = make_float4(acc[0], acc[1], acc[2], acc[3]);
    __syncthreads();
    if (!chalf) {
        float4 r = rbuf[im][lane];
        *(float4*)&h2[(i0 + im) * 256 + ln15 * 16 + g * 4] =
            make_float4(acc[0] + r.x, acc[1] + r.y, acc[2] + r.z, acc[3] + r.w);
    }
}

// ---------------------------------------------------------------------------
// K3: fc1(relu) -> fc2(relu) -> fc3. One block = 8 batch rows, 256 threads.
// ---------------------------------------------------------------------------
__global__ __launch_bounds__(256) void k_fc(
    const float* __restrict__ h2,
    const float* __restrict__ w1, const float* __restrict__ b1,
    const float* __restrict__ w2, const float* __restrict__ b2,
    const float* __restrict__ w3, const float* __restrict__ b3,
    float* __restrict__ out)
{
    __shared__ float xin[8][260];
    __shared__ float a1[8][120];
    __shared__ float a2[8][84];
    const int tid = threadIdx.x;
    const int r0 = blockIdx.x * 8;

    for (int i = tid; i < 2048; i += 256)
        xin[i >> 8][i & 255] = h2[r0 * 256 + i];
    __syncthreads();

    for (int idx = tid; idx < 960; idx += 256) {      // 120 out x 8 rows
        const int o = idx >> 3, r = idx & 7;
        const float* w = w1 + o * 256;
        float s = 0.0f;
#pragma unroll 8
        for (int k = 0; k < 64; ++k) {
            float4 wv = ((const float4*)w)[k];
            float4 xv = *(const float4*)(&xin[r][k * 4]);
            s += wv.x * xv.x + wv.y * xv.y + wv.z * xv.z + wv.w * xv.w;
        }
        a1[r][o] = fmaxf(s + b1[o], 0.0f);
    }
    __syncthreads();

    for (int idx = tid; idx < 672; idx += 256) {      // 84 out x 8 rows
        const int o = idx >> 3, r = idx & 7;
        const float* w = w2 + o * 120;
        float s = 0.0f;
#pragma unroll
        for (int k = 0; k < 30; ++k) {
            float4 wv = ((const float4*)w)[k];
            float4 xv = *(const float4*)(&a1[r][k * 4]);
            s += wv.x * xv.x + wv.y * xv.y + wv.z * xv.z + wv.w * xv.w;
        }
        a2[r][o] = fmaxf(s + b2[o], 0.0f);
    }
    __syncthreads();

    for (int idx = tid; idx < 496; idx += 256) {      // 62 out x 8 rows
        const int o = idx >> 3, r = idx & 7;
        const float* w = w3 + o * 84;
        float s = 0.0f;
#pragma unroll
        for (int k = 0; k < 21; ++k) {
            float4 wv = ((const float4*)w)[k];
            float4 xv = *(const float4*)(&a2[r][k * 4]);
            s += wv.x * xv.x + wv.y * xv.y + wv.z * xv.z + wv.w * xv.w;
        }
        out[(r0 + r) * 62 + o] = s + b3[o];
    }
}

// ---------------------------------------------------------------------------
extern "C" void kernel_launch(void* const* d_in, const int* in_sizes, int n_in,
                              void* d_out, int out_size, void* d_ws, size_t ws_size,
                              hipStream_t stream)
{
    (void)in_sizes; (void)n_in; (void)out_size; (void)ws_size;
    const float* x      = (const float*)d_in[0];
    const float* c1_bw  = (const float*)d_in[1];
    const float* c1_sw  = (const float*)d_in[2];
    const float* c1_sc  = (const float*)d_in[3];
    const float* c2_bw  = (const float*)d_in[4];
    const float* c2_sw  = (const float*)d_in[5];
    const float* c2_sc  = (const float*)d_in[6];
    const float* fc1_w  = (const float*)d_in[7];
    const float* fc1_b  = (const float*)d_in[8];
    const float* fc2_w  = (const float*)d_in[9];
    const float* fc2_b  = (const float*)d_in[10];
    const float* fc3_w  = (const float*)d_in[11];
    const float* fc3_b  = (const float*)d_in[12];
    float* out = (float*)d_out;

    char* wsb = (char*)d_ws;
    f16*   W1g = (f16*)(wsb);                  //  9216 f16  = 18432 B
    f16*   W2g = (f16*)(wsb + 18432);          // 55296 f16  = 110592 B
    float* h1  = (float*)(wsb + 131072);       // 1024*6*144 f32 = 3538944 B
    float* h2  = (float*)(wsb + 131072 + 3538944);   // 1024*256 f32

    hipLaunchKernelGGL(k_prep, dim3(256), dim3(256), 0, stream,
                       c1_bw, c1_sw, c1_sc, c2_bw, c2_sw, c2_sc, W1g, W2g);
    hipLaunchKernelGGL(k_conv1, dim3(1024), dim3(192), 0, stream, x, W1g, h1);
    hipLaunchKernelGGL(k_conv2, dim3(512), dim3(256), 0, stream, h1, W2g, h2);
    hipLaunchKernelGGL(k_fc, dim3(128), dim3(256), 0, stream,
                       h2, fc1_w, fc1_b, fc2_w, fc2_b, fc3_w, fc3_b, out);
}

// Round 7
// 45.573 us; speedup vs baseline: 6.2054x; 1.1313x over previous
//
#include <hip/hip_runtime.h>

// ---------------------------------------------------------------------------
// LeNet5-KAN on MI355X.  R7: conv1+conv2 fused per-image (h1 stays in LDS).
// MFMA f16 in / f32 accum; avg-pool folded into weights (stride-2 conv6x6).
//
// GEMM view per conv:  out[p][o] = sum_K feat16[elem(p,tap)][k] * W[tap,k][o]
//   K = taps(36) x kpad(16): k0..7 = cubic B-spline bases, k8 = relu, rest 0.
//   A-frag: lane&15 = out px, lane>>4 = k-group (16B ds_read_b128)
//   B-frag: lane&15 = o,     lane>>4 = same k-group (16B global load, L2)
//   C     : col = lane&15 (o), row = (lane>>4)*4 + reg
// A and B use the identical (group,elem)->k map, so the MFMA-internal k
// permutation cancels (sum over k is permutation invariant).
// feat LDS chunks (16B) XOR-swizzled: ch ^= (ch>>3)&7.
// ---------------------------------------------------------------------------

typedef _Float16 f16;
typedef f16 f16x8 __attribute__((ext_vector_type(8)));
typedef float f32x4 __attribute__((ext_vector_type(4)));

#define ONE_SIXTH 0.16666666666666666f

__device__ __forceinline__ void spline9(float v, float* __restrict__ f) {
    float u  = 2.5f * v + 5.5f;
    bool valid = (u >= 0.0f) && (u < 11.0f);
    float fi = floorf(u);
    int   i  = (int)fi;
    float w  = u - fi;
    float omw = 1.0f - w;
    float w2 = w * w, w3 = w2 * w;
    float c0 = omw * omw * omw * ONE_SIXTH;
    float c1 = (3.0f * w3 - 6.0f * w2 + 4.0f) * ONE_SIXTH;
    float c2 = (-3.0f * w3 + 3.0f * w2 + 3.0f * w + 1.0f) * ONE_SIXTH;
    float c3 = w3 * ONE_SIXTH;
    int j0 = i - 3;
#pragma unroll
    for (int j = 0; j < 8; ++j) {
        int d = j - j0;
        float val = (d == 0) ? c0 : (d == 1) ? c1 : (d == 2) ? c2 : (d == 3) ? c3 : 0.0f;
        f[j] = valid ? val : 0.0f;
    }
    f[8] = fmaxf(v, 0.0f);
}

// two 16B chunks: c0 = bases[0..7] as f16, c1 = {relu, 0 x7}
__device__ __forceinline__ void spline_chunks(float v, uint4& u0, uint4& u1) {
    float f[9];
    spline9(v, f);
    union { f16 h[8]; uint4 u; } a, b;
#pragma unroll
    for (int j = 0; j < 8; ++j) a.h[j] = (f16)f[j];
    b.u.x = 0u; b.u.y = 0u; b.u.z = 0u; b.u.w = 0u;
    b.h[0] = (f16)f[8];
    u0 = a.u; u1 = b.u;
}

// ---------------------------------------------------------------------------
// K0: build pooled-conv weights, f16.
// W1g[(tap*16 + o)*16 + k], tap<36, o<16 (6 valid), k<16 (9 valid)
// W2g[((c*36 + tap)*16 + o)*16 + k], c<6
// w'[ey][ex] = 0.25 * sum_{a,b in {0,1}, 0<=ey-a<5, 0<=ex-b<5} w[ey-a][ex-b]
// ---------------------------------------------------------------------------
__global__ __launch_bounds__(256) void k_prep(
    const float* __restrict__ c1_bw, const float* __restrict__ c1_sw,
    const float* __restrict__ c1_sc,
    const float* __restrict__ c2_bw, const float* __restrict__ c2_sw,
    const float* __restrict__ c2_sc,
    f16* __restrict__ W1g, f16* __restrict__ W2g)
{
    int t = blockIdx.x * 256 + threadIdx.x;
    if (t < 9216) {
        int tap = t >> 8, r = t & 255;
        int o = r >> 4, k = r & 15;
        float val = 0.0f;
        if (o < 6 && k < 9) {
            int ey = tap / 6, ex = tap - 6 * ey;
            float s = 0.0f;
            for (int a = 0; a < 2; ++a) {
                for (int b = 0; b < 2; ++b) {
                    int dy = ey - a, dx = ex - b;
                    if (dy >= 0 && dy < 5 && dx >= 0 && dx < 5) {
                        int idx = o * 25 + dy * 5 + dx;
                        s += (k == 8) ? c1_bw[idx] : c1_sw[idx * 8 + k] * c1_sc[idx];
                    }
                }
            }
            val = 0.25f * s;
        }
        W1g[t] = (f16)val;
    }
    if (t < 55296) {
        int c = t / 9216, r = t - c * 9216;
        int tap = r >> 8, rr = r & 255;
        int o = rr >> 4, k = rr & 15;
        float val = 0.0f;
        if (k < 9) {
            int ey = tap / 6, ex = tap - 6 * ey;
            float s = 0.0f;
            for (int a = 0; a < 2; ++a) {
                for (int b = 0; b < 2; ++b) {
                    int dy = ey - a, dx = ex - b;
                    if (dy >= 0 && dy < 5 && dx >= 0 && dx < 5) {
                        int idx = o * 150 + c * 25 + dy * 5 + dx;
                        s += (k == 8) ? c2_bw[idx] : c2_sw[idx * 8 + k] * c2_sc[idx];
                    }
                }
            }
            val = 0.25f * s;
        }
        W2g[t] = (f16)val;
    }
}

// ---------------------------------------------------------------------------
// K1: fused conv1+pool -> conv2+pool. One block = 1 image, 192 thr = 3 waves.
// Phase A: spline-stage x (784 elems) into feat LDS.
// Phase B: conv1 MFMA (3 waves x 3 M-tiles x 18 kc); C-frags -> h1 in LDS.
// Phase C: spline-stage h1 (864 elems) into feat LDS (re-aliased).
// Phase D: conv2 MFMA, K split 3 ways (36 chunks/wave); LDS reduce -> h2.
// ---------------------------------------------------------------------------
__global__ __launch_bounds__(192, 3) void k_conv12(
    const float* __restrict__ x, const f16* __restrict__ W1g,
    const f16* __restrict__ W2g, float* __restrict__ h2)
{
    __shared__ uint4  feat[1728];    // A: 1568 used; C: 1728 used (aliased)
    __shared__ float  h1l[864];      // conv1 output [o][144] f32
    __shared__ float4 rbuf[2][64];   // conv2 partial sums (waves 1,2)

    const int img = blockIdx.x;
    const int tid = threadIdx.x;
    const int lane = tid & 63, wv = tid >> 6;
    const int ln15 = lane & 15, g = lane >> 4;
    const int gh = g & 1, gt = g >> 1;

    // ---- Phase A: stage feat(x) ----
    for (int e = tid; e < 784; e += 192) {
        uint4 u0, u1;
        spline_chunks(x[img * 784 + e], u0, u1);
        int ch = e * 2;
        int q = (ch >> 3) & 7;
        feat[ch ^ q] = u0;
        feat[(ch + 1) ^ q] = u1;
    }
    __syncthreads();

    // ---- Phase B: conv1 ----
    {
        int ebase[3];
#pragma unroll
        for (int t = 0; t < 3; ++t) {
            int p = (wv * 3 + t) * 16 + ln15;
            int py = p / 12, px = p - py * 12;
            ebase[t] = py * 56 + px * 2;            // (2py)*28 + 2px
        }
        const f16* bptr = W1g + (gt * 16 + ln15) * 16 + gh * 8;
        f16x8 bfrag = *(const f16x8*)bptr;
        f32x4 acc[3] = {{0,0,0,0},{0,0,0,0},{0,0,0,0}};

        for (int kc = 0; kc < 18; ++kc) {
            int tap = kc * 2 + gt;
            int ey = (tap * 171) >> 10, ex = tap - ey * 6;
            int eoff = ey * 28 + ex;
            f16x8 bcur = bfrag;
            bptr += 512;
            bfrag = *(const f16x8*)bptr;            // overreads into W2g: safe
#pragma unroll
            for (int t = 0; t < 3; ++t) {
                int ch = (ebase[t] + eoff) * 2 + gh;
                ch ^= (ch >> 3) & 7;
                f16x8 afrag = *(const f16x8*)(&feat[ch]);
                acc[t] = __builtin_amdgcn_mfma_f32_16x16x32_f16(afrag, bcur, acc[t], 0, 0, 0);
            }
        }
        if (ln15 < 6) {
#pragma unroll
            for (int t = 0; t < 3; ++t) {
                int p0 = (wv * 3 + t) * 16 + g * 4;     // row = g*4 + reg
                *(float4*)&h1l[ln15 * 144 + p0] =
                    make_float4(acc[t][0], acc[t][1], acc[t][2], acc[t][3]);
            }
        }
    }
    __syncthreads();    // feat reads done + h1l visible

    // ---- Phase C: stage feat(h1) ----
    for (int e = tid; e < 864; e += 192) {
        uint4 u0, u1;
        spline_chunks(h1l[e], u0, u1);
        int ch = e * 2;
        int q = (ch >> 3) & 7;
        feat[ch ^ q] = u0;
        feat[(ch + 1) ^ q] = u1;
    }
    __syncthreads();

    // ---- Phase D: conv2, K split over 3 waves ----
    {
        const int py = ln15 >> 2, px = ln15 & 3;
        const int epx = py * 24 + px * 2;           // (2py)*12 + 2px
        const int kk0 = wv * 36;
        const f16* bptr = W2g + ((kk0 * 2 + gt) * 16 + ln15) * 16 + gh * 8;
        f16x8 bfrag = *(const f16x8*)bptr;
        f32x4 acc = {0, 0, 0, 0};

        for (int i = 0; i < 36; ++i) {
            int kk = kk0 + i;
            int c = kk / 18, tk = kk - c * 18;
            int tap = tk * 2 + gt;
            int ey = (tap * 171) >> 10, ex = tap - ey * 6;
            f16x8 bcur = bfrag;
            bptr += 512;
            bfrag = *(const f16x8*)bptr;            // overreads past W2g: padded
            int elem = c * 144 + epx + ey * 12 + ex;
            int ch = elem * 2 + gh;
            ch ^= (ch >> 3) & 7;
            f16x8 afrag = *(const f16x8*)(&feat[ch]);
            acc = __builtin_amdgcn_mfma_f32_16x16x32_f16(afrag, bcur, acc, 0, 0, 0);
        }

        if (wv) rbuf[wv - 1][lane] = make_float4(acc[0], acc[1], acc[2], acc[3]);
        __syncthreads();
        if (wv == 0) {
            float4 r0 = rbuf[0][lane], r1 = rbuf[1][lane];
            *(float4*)&h2[img * 256 + ln15 * 16 + g * 4] =
                make_float4(acc[0] + r0.x + r1.x, acc[1] + r0.y + r1.y,
                            acc[2] + r0.z + r1.z, acc[3] + r0.w + r1.w);
        }
    }
}

// ---------------------------------------------------------------------------
// K3: fc1(relu) -> fc2(relu) -> fc3. One block = 8 batch rows, 256 threads.
// ---------------------------------------------------------------------------
__global__ __launch_bounds__(256) void k_fc(
    const float* __restrict__ h2,
    const float* __restrict__ w1, const float* __restrict__ b1,
    const float* __restrict__ w2, const float* __restrict__ b2,
    const float* __restrict__ w3, const float* __restrict__ b3,
    float* __restrict__ out)
{
    __shared__ float xin[8][260];
    __shared__ float a1[8][120];
    __shared__ float a2[8][84];
    const int tid = threadIdx.x;
    const int r0 = blockIdx.x * 8;

    for (int i = tid; i < 2048; i += 256)
        xin[i >> 8][i & 255] = h2[r0 * 256 + i];
    __syncthreads();

    for (int idx = tid; idx < 960; idx += 256) {      // 120 out x 8 rows
        const int o = idx >> 3, r = idx & 7;
        const float* w = w1 + o * 256;
        float s = 0.0f;
#pragma unroll 8
        for (int k = 0; k < 64; ++k) {
            float4 wv = ((const float4*)w)[k];
            float4 xv = *(const float4*)(&xin[r][k * 4]);
            s += wv.x * xv.x + wv.y * xv.y + wv.z * xv.z + wv.w * xv.w;
        }
        a1[r][o] = fmaxf(s + b1[o], 0.0f);
    }
    __syncthreads();

    for (int idx = tid; idx < 672; idx += 256) {      // 84 out x 8 rows
        const int o = idx >> 3, r = idx & 7;
        const float* w = w2 + o * 120;
        float s = 0.0f;
#pragma unroll
        for (int k = 0; k < 30; ++k) {
            float4 wv = ((const float4*)w)[k];
            float4 xv = *(const float4*)(&a1[r][k * 4]);
            s += wv.x * xv.x + wv.y * xv.y + wv.z * xv.z + wv.w * xv.w;
        }
        a2[r][o] = fmaxf(s + b2[o], 0.0f);
    }
    __syncthreads();

    for (int idx = tid; idx < 496; idx += 256) {      // 62 out x 8 rows
        const int o = idx >> 3, r = idx & 7;
        const float* w = w3 + o * 84;
        float s = 0.0f;
#pragma unroll
        for (int k = 0; k < 21; ++k) {
            float4 wv = ((const float4*)w)[k];
            float4 xv = *(const float4*)(&a2[r][k * 4]);
            s += wv.x * xv.x + wv.y * xv.y + wv.z * xv.z + wv.w * xv.w;
        }
        out[(r0 + r) * 62 + o] = s + b3[o];
    }
}

// ---------------------------------------------------------------------------
extern "C" void kernel_launch(void* const* d_in, const int* in_sizes, int n_in,
                              void* d_out, int out_size, void* d_ws, size_t ws_size,
                              hipStream_t stream)
{
    (void)in_sizes; (void)n_in; (void)out_size; (void)ws_size;
    const float* x      = (const float*)d_in[0];
    const float* c1_bw  = (const float*)d_in[1];
    const float* c1_sw  = (const float*)d_in[2];
    const float* c1_sc  = (const float*)d_in[3];
    const float* c2_bw  = (const float*)d_in[4];
    const float* c2_sw  = (const float*)d_in[5];
    const float* c2_sc  = (const float*)d_in[6];
    const float* fc1_w  = (const float*)d_in[7];
    const float* fc1_b  = (const float*)d_in[8];
    const float* fc2_w  = (const float*)d_in[9];
    const float* fc2_b  = (const float*)d_in[10];
    const float* fc3_w  = (const float*)d_in[11];
    const float* fc3_b  = (const float*)d_in[12];
    float* out = (float*)d_out;

    char* wsb = (char*)d_ws;
    f16*   W1g = (f16*)(wsb);                  //  9216 f16 = 18432 B
    f16*   W2g = (f16*)(wsb + 18432);          // 55296 f16 = 110592 B (+pad)
    float* h2  = (float*)(wsb + 131072);       // 1024*256 f32

    hipLaunchKernelGGL(k_prep, dim3(256), dim3(256), 0, stream,
                       c1_bw, c1_sw, c1_sc, c2_bw, c2_sw, c2_sc, W1g, W2g);
    hipLaunchKernelGGL(k_conv12, dim3(1024), dim3(192), 0, stream,
                       x, W1g, W2g, h2);
    hipLaunchKernelGGL(k_fc, dim3(128), dim3(256), 0, stream,
                       h2, fc1_w, fc1_b, fc2_w, fc2_b, fc3_w, fc3_b, out);
}